// Round 5
// baseline (1153.570 us; speedup 1.0000x reference)
//
#include <hip/hip_runtime.h>
#include <hip/hip_fp16.h>

typedef _Float16 half8 __attribute__((ext_vector_type(8)));
typedef _Float16 half4 __attribute__((ext_vector_type(4)));
typedef float floatx4 __attribute__((ext_vector_type(4)));

#define TT 512
#define EE 100
#define NBATCH 16
#define NBLK 64
#define WS_NEED ((size_t)NBLK * TT * 2048 * sizeof(_Float16))

__device__ __forceinline__ float sigm(float x) {
    return __builtin_amdgcn_rcpf(1.0f + __expf(-x));
}
__device__ __forceinline__ float tanh_(float x) {
    return __builtin_amdgcn_rcpf(1.0f + __expf(-2.0f * x)) * 2.0f - 1.0f;
}

// ---- pre-pass: X (fp32 [B][T][100]) -> fragment-ordered fp16 in d_ws ----
// 512 blocks x 256 thr; block (blk, tchunk) covers 64 timesteps (fixes the
// 32768-tiny-block launch-rate bound of round 4: ~280 us -> ~70 us).
extern "C" __global__ void __launch_bounds__(256)
xfrag_prep(const float* __restrict__ X, _Float16* __restrict__ xw)
{
    const int blk = blockIdx.x >> 3;
    const int tc  = blockIdx.x & 7;
    const int tid = threadIdx.x;
    const int c   = tid >> 4, m = tid & 15;
    const int k0  = 8 * c;
    const float* xrow = X + (size_t)(blk * 16 + m) * TT * EE + k0;
    _Float16*    wrow = xw + (size_t)(blk * TT) * 2048 + c * 128 + m * 8;
    for (int tt = 0; tt < 64; ++tt) {
        const int t = tc * 64 + tt;
        half8 v;
#pragma unroll
        for (int j = 0; j < 8; ++j) v[j] = (_Float16)0.0f;
        const float* p = xrow + t * EE;
        if (k0 + 8 <= EE) {
            float4 lo = *(const float4*)p;
            float4 hi = *(const float4*)(p + 4);
            v[0] = (_Float16)lo.x; v[1] = (_Float16)lo.y; v[2] = (_Float16)lo.z; v[3] = (_Float16)lo.w;
            v[4] = (_Float16)hi.x; v[5] = (_Float16)hi.y; v[6] = (_Float16)hi.z; v[7] = (_Float16)hi.w;
        } else if (k0 < EE) {   // c == 12: k 96..99 + bias-one at k=100
            float4 lo = *(const float4*)p;
            v[0] = (_Float16)lo.x; v[1] = (_Float16)lo.y; v[2] = (_Float16)lo.z; v[3] = (_Float16)lo.w;
            v[4] = (_Float16)1.0f;
        }
        *(half8*)&wrow[(size_t)t * 2048] = v;
    }
}

// ---- main: 64 blocks x 512 threads (8 waves), merged-h1-read K-loop ----
// Iteration t computes BOTH a2(t-1) (L2 gates) and a1(t) (L1 gates) from a
// single read of h1(t-1) fragments (6 b128/wave/step instead of 10).
// Buffer parities: h1(tau) -> h1b[tau&1]; h2(tau) -> h2b[tau&1].
template<int USE_WS>
__global__ void __launch_bounds__(512, 1)
lstm_mfma4(const float* __restrict__ X, const _Float16* __restrict__ xw,
           const float* __restrict__ W1ih, const float* __restrict__ W1hh,
           const float* __restrict__ b1i,  const float* __restrict__ b1h,
           const float* __restrict__ W2ih, const float* __restrict__ W2hh,
           const float* __restrict__ b2i,  const float* __restrict__ b2h,
           const float* __restrict__ fc1w, const float* __restrict__ fc1b,
           const float* __restrict__ fc2w, const float* __restrict__ fc2b,
           float* __restrict__ out)
{
    const int tid  = threadIdx.x;
    const int w    = tid >> 6;
    const int lane = tid & 63;
    const int q    = lane >> 4;
    const int m    = lane & 15;
    const int b0   = blockIdx.x * NBATCH;
    const int gh   = w >> 2;      // 0: L2 gates i,f   1: L2 gates g,o
    const int p2   = w & 3;       // L2 unit-slice

    __shared__ __align__(16) _Float16 h1b[2][4][4][16][8];   // 8 KB
    __shared__ __align__(16) _Float16 h2b[2][2][4][16][8];   // 4 KB
    __shared__ __align__(16) _Float16 gob[2][16][68];        // 4.25 KB
    __shared__ float fca[NBATCH][32];

    {   // zero-init recurrent LDS state (h1(-1), h2(-2), h2(-1))
        _Float16* p = &h1b[0][0][0][0][0];
        for (int i = tid; i < 2 * 2048; i += 512) p[i] = (_Float16)0.0f;
        p = &h2b[0][0][0][0][0];
        for (int i = tid; i < 2 * 1024; i += 512) p[i] = (_Float16)0.0f;
    }

    // ---- weight fragments (A-layout: row=m, k=32s+8q+j) ----
    half8 w1ihf[4][4], w1hhf[4][4], w2ihf[2][4], w2hhf[2][2];
    floatx4 bias2v[2];
#pragma unroll
    for (int g = 0; g < 4; ++g) {
        const int r = g * 128 + 16 * w + m;
        const float bias = b1i[r] + b1h[r];
#pragma unroll
        for (int s = 0; s < 4; ++s) {
            half8 f;
#pragma unroll
            for (int j = 0; j < 8; ++j) {
                const int k = 32 * s + 8 * q + j;
                float v = 0.0f;
                if (k < EE) v = W1ih[r * EE + k];
                else if (k == EE) v = bias;          // pairs with x bias-one column
                f[j] = (_Float16)v;
            }
            w1ihf[g][s] = f;
        }
#pragma unroll
        for (int s = 0; s < 4; ++s) {
            half8 f;
#pragma unroll
            for (int j = 0; j < 8; ++j) f[j] = (_Float16)W1hh[r * 128 + 32 * s + 8 * q + j];
            w1hhf[g][s] = f;
        }
    }
#pragma unroll
    for (int tau = 0; tau < 2; ++tau) {
        const int g = 2 * gh + tau;
        const int r = g * 64 + 16 * p2 + m;
#pragma unroll
        for (int s = 0; s < 4; ++s) {
            half8 f;
#pragma unroll
            for (int j = 0; j < 8; ++j) f[j] = (_Float16)W2ih[r * 128 + 32 * s + 8 * q + j];
            w2ihf[tau][s] = f;
        }
#pragma unroll
        for (int s = 0; s < 2; ++s) {
            half8 f;
#pragma unroll
            for (int j = 0; j < 8; ++j) f[j] = (_Float16)W2hh[r * 64 + 32 * s + 8 * q + j];
            w2hhf[tau][s] = f;
        }
#pragma unroll
        for (int reg = 0; reg < 4; ++reg) {
            const int rr = g * 64 + 16 * p2 + 4 * q + reg;
            bias2v[tau][reg] = b2i[rr] + b2h[rr];
        }
    }

    // ---- x fragments: 2-stage register pipeline from d_ws (or X inline) ----
    const _Float16* xwb = xw + (size_t)blockIdx.x * TT * 2048;
    const int foff = q * 128 + m * 8;
    const float* xrow = X + (size_t)(b0 + m) * TT * EE;   // fallback path
    half8 xcur[4], xnxt[4];

    auto load_x = [&](int t, half8* dst) {
        if (USE_WS) {
            const _Float16* xp = xwb + (size_t)t * 2048 + foff;
#pragma unroll
            for (int s = 0; s < 4; ++s) dst[s] = *(const half8*)(xp + s * 512);
        } else {
            const float* p = xrow + t * EE + 8 * q;
#pragma unroll
            for (int s = 0; s < 3; ++s) {
                float4 lo = *(const float4*)(p + 32 * s);
                float4 hi = *(const float4*)(p + 32 * s + 4);
                half8 f;
                f[0] = (_Float16)lo.x; f[1] = (_Float16)lo.y; f[2] = (_Float16)lo.z; f[3] = (_Float16)lo.w;
                f[4] = (_Float16)hi.x; f[5] = (_Float16)hi.y; f[6] = (_Float16)hi.z; f[7] = (_Float16)hi.w;
                dst[s] = f;
            }
            half8 f;
#pragma unroll
            for (int j = 0; j < 8; ++j) f[j] = (_Float16)0.0f;
            if (q == 0) {   // k = 96..100: 4 data + bias-one
                float4 lo = *(const float4*)(p + 96);
                f[0] = (_Float16)lo.x; f[1] = (_Float16)lo.y; f[2] = (_Float16)lo.z; f[3] = (_Float16)lo.w;
                f[4] = (_Float16)1.0f;
            }
            dst[3] = f;
        }
    };

    __syncthreads();
    load_x(0, xcur);
    load_x(1, xnxt);

    floatx4 c1 = {0.f, 0.f, 0.f, 0.f};
    floatx4 c2 = {0.f, 0.f, 0.f, 0.f};
    const int vv = 2 * w + (q >> 1);   // h1 fragment slot
    const int v2 = 2 * p2 + (q >> 1);  // h2 fragment slot
    const int jj = 4 * (q & 1);

#pragma unroll 1
    for (int t = 0; t < TT; ++t) {
        const int cur = t & 1, nxt = cur ^ 1;

        // issue x(t+1) loads first — drained at barrier A, ~full phase away
        if (t + 1 < TT) load_x(t + 1, xnxt);

        // single h1(t-1) fragment read serves BOTH W1hh(a1) and W2ih(a2)
        const _Float16* hp  = &h1b[nxt][0][0][0][0] + foff;
        const _Float16* h2p = &h2b[cur][0][0][0][0] + foff;
        half8 bh0 = *(const half8*)(hp);
        half8 bh1 = *(const half8*)(hp + 512);
        half8 bh2 = *(const half8*)(hp + 1024);
        half8 bh3 = *(const half8*)(hp + 1536);
        half8 b20 = *(const half8*)(h2p);
        half8 b21 = *(const half8*)(h2p + 512);

        // a1-ih: register-only MFMAs issue while the ds_reads are in flight
        floatx4 a1[4];
#pragma unroll
        for (int g = 0; g < 4; ++g) a1[g] = (floatx4){0.f, 0.f, 0.f, 0.f};
#pragma unroll
        for (int s = 0; s < 4; ++s)
#pragma unroll
            for (int g = 0; g < 4; ++g)
                a1[g] = __builtin_amdgcn_mfma_f32_16x16x32_f16(w1ihf[g][s], xcur[s], a1[g], 0, 0, 0);

        // a2(t-1): L2 gates from h1(t-1), h2(t-2)
        floatx4 a2[2] = { bias2v[0], bias2v[1] };
        a2[0] = __builtin_amdgcn_mfma_f32_16x16x32_f16(w2ihf[0][0], bh0, a2[0], 0, 0, 0);
        a2[1] = __builtin_amdgcn_mfma_f32_16x16x32_f16(w2ihf[1][0], bh0, a2[1], 0, 0, 0);
        a2[0] = __builtin_amdgcn_mfma_f32_16x16x32_f16(w2ihf[0][1], bh1, a2[0], 0, 0, 0);
        a2[1] = __builtin_amdgcn_mfma_f32_16x16x32_f16(w2ihf[1][1], bh1, a2[1], 0, 0, 0);
        a2[0] = __builtin_amdgcn_mfma_f32_16x16x32_f16(w2ihf[0][2], bh2, a2[0], 0, 0, 0);
        a2[1] = __builtin_amdgcn_mfma_f32_16x16x32_f16(w2ihf[1][2], bh2, a2[1], 0, 0, 0);
        a2[0] = __builtin_amdgcn_mfma_f32_16x16x32_f16(w2ihf[0][3], bh3, a2[0], 0, 0, 0);
        a2[1] = __builtin_amdgcn_mfma_f32_16x16x32_f16(w2ihf[1][3], bh3, a2[1], 0, 0, 0);
        a2[0] = __builtin_amdgcn_mfma_f32_16x16x32_f16(w2hhf[0][0], b20, a2[0], 0, 0, 0);
        a2[1] = __builtin_amdgcn_mfma_f32_16x16x32_f16(w2hhf[1][0], b20, a2[1], 0, 0, 0);
        a2[0] = __builtin_amdgcn_mfma_f32_16x16x32_f16(w2hhf[0][1], b21, a2[0], 0, 0, 0);
        a2[1] = __builtin_amdgcn_mfma_f32_16x16x32_f16(w2hhf[1][1], b21, a2[1], 0, 0, 0);

        // a1-hh: reuse the same bh fragments
#pragma unroll
        for (int g = 0; g < 4; ++g) {
            a1[g] = __builtin_amdgcn_mfma_f32_16x16x32_f16(w1hhf[g][0], bh0, a1[g], 0, 0, 0);
            a1[g] = __builtin_amdgcn_mfma_f32_16x16x32_f16(w1hhf[g][1], bh1, a1[g], 0, 0, 0);
            a1[g] = __builtin_amdgcn_mfma_f32_16x16x32_f16(w1hhf[g][2], bh2, a1[g], 0, 0, 0);
            a1[g] = __builtin_amdgcn_mfma_f32_16x16x32_f16(w1hhf[g][3], bh3, a1[g], 0, 0, 0);
        }

        // g/o waves: activate L2 gates of step t-1, hand to i/f waves
        if (gh == 1) {
            half4 tg, so;
#pragma unroll
            for (int r = 0; r < 4; ++r) {
                tg[r] = (_Float16)tanh_(a2[0][r]);
                so[r] = (_Float16)sigm(a2[1][r]);
            }
            *(half4*)&gob[0][m][16 * p2 + 4 * q] = tg;
            *(half4*)&gob[1][m][16 * p2 + 4 * q] = so;
        }

        // ep1: L1 cell update (in-register) -> h1(t)
        {
            half4 hv;
#pragma unroll
            for (int r = 0; r < 4; ++r) {
                const float iv = sigm(a1[0][r]);
                const float fv = sigm(a1[1][r]);
                const float gv = tanh_(a1[2][r]);
                const float ov = sigm(a1[3][r]);
                const float c  = fv * c1[r] + iv * gv;
                c1[r] = c;
                hv[r] = (_Float16)(ov * tanh_(c));
            }
            *(half4*)&h1b[cur][vv >> 2][vv & 3][m][jj] = hv;
        }
        __syncthreads();   // A: gob + h1(t) visible

        // i/f waves: c2/h2(t-1) update (skip at t=0: h2(-1) stays zero)
        if (gh == 0 && t > 0) {
            half4 tg = *(const half4*)&gob[0][m][16 * p2 + 4 * q];
            half4 so = *(const half4*)&gob[1][m][16 * p2 + 4 * q];
            half4 hv;
#pragma unroll
            for (int r = 0; r < 4; ++r) {
                const float c = sigm(a2[1][r]) * c2[r] + sigm(a2[0][r]) * (float)tg[r];
                c2[r] = c;
                hv[r] = (_Float16)((float)so[r] * tanh_(c));
            }
            *(half4*)&h2b[nxt][v2 >> 2][v2 & 3][m][jj] = hv;
        }
#pragma unroll
        for (int s = 0; s < 4; ++s) xcur[s] = xnxt[s];
        __syncthreads();   // B: h2(t-1) visible for next iteration's b2 read
    }

    // ---- tail: L2 step TT-1 (a2 uses h1(TT-1), h2(TT-2)) ----
    {
        const _Float16* hp  = &h1b[1][0][0][0][0] + foff;    // h1(TT-1): parity 1
        const _Float16* h2p = &h2b[0][0][0][0][0] + foff;    // h2(TT-2): parity 0
        floatx4 a2[2] = { bias2v[0], bias2v[1] };
#pragma unroll
        for (int s = 0; s < 4; ++s) {
            half8 bh = *(const half8*)(hp + s * 512);
            a2[0] = __builtin_amdgcn_mfma_f32_16x16x32_f16(w2ihf[0][s], bh, a2[0], 0, 0, 0);
            a2[1] = __builtin_amdgcn_mfma_f32_16x16x32_f16(w2ihf[1][s], bh, a2[1], 0, 0, 0);
        }
#pragma unroll
        for (int s = 0; s < 2; ++s) {
            half8 b2v = *(const half8*)(h2p + s * 512);
            a2[0] = __builtin_amdgcn_mfma_f32_16x16x32_f16(w2hhf[0][s], b2v, a2[0], 0, 0, 0);
            a2[1] = __builtin_amdgcn_mfma_f32_16x16x32_f16(w2hhf[1][s], b2v, a2[1], 0, 0, 0);
        }
        if (gh == 1) {
            half4 tg, so;
#pragma unroll
            for (int r = 0; r < 4; ++r) {
                tg[r] = (_Float16)tanh_(a2[0][r]);
                so[r] = (_Float16)sigm(a2[1][r]);
            }
            *(half4*)&gob[0][m][16 * p2 + 4 * q] = tg;
            *(half4*)&gob[1][m][16 * p2 + 4 * q] = so;
        }
        __syncthreads();
        if (gh == 0) {
            half4 tg = *(const half4*)&gob[0][m][16 * p2 + 4 * q];
            half4 so = *(const half4*)&gob[1][m][16 * p2 + 4 * q];
            half4 hv;
#pragma unroll
            for (int r = 0; r < 4; ++r) {
                const float c = sigm(a2[1][r]) * c2[r] + sigm(a2[0][r]) * (float)tg[r];
                hv[r] = (_Float16)((float)so[r] * tanh_(c));
            }
            *(half4*)&h2b[1][v2 >> 2][v2 & 3][m][jj] = hv;   // h2(TT-1): parity 1
        }
        __syncthreads();
    }

    // ---- FC head ----
    {
        const int nb = tid >> 5, o = tid & 31;
        float s = fc1b[o];
#pragma unroll
        for (int k = 0; k < 64; ++k)
            s += fc1w[o * 64 + k] * (float)h2b[1][k >> 5][(k >> 3) & 3][nb][k & 7];
        fca[nb][o] = fmaxf(s, 0.0f);
    }
    __syncthreads();
    if (tid < NBATCH) {
        float s = fc2b[0];
#pragma unroll
        for (int k = 0; k < 32; ++k) s += fc2w[k] * fca[tid][k];
        out[b0 + tid] = sigm(s);
    }
}

extern "C" void kernel_launch(void* const* d_in, const int* in_sizes, int n_in,
                              void* d_out, int out_size, void* d_ws, size_t ws_size,
                              hipStream_t stream) {
    const float* X    = (const float*)d_in[0];
    const float* W1ih = (const float*)d_in[1];
    const float* W1hh = (const float*)d_in[2];
    const float* b1i  = (const float*)d_in[3];
    const float* b1h  = (const float*)d_in[4];
    const float* W2ih = (const float*)d_in[5];
    const float* W2hh = (const float*)d_in[6];
    const float* b2i  = (const float*)d_in[7];
    const float* b2h  = (const float*)d_in[8];
    const float* fc1w = (const float*)d_in[9];
    const float* fc1b = (const float*)d_in[10];
    const float* fc2w = (const float*)d_in[11];
    const float* fc2b = (const float*)d_in[12];
    _Float16* xw = (_Float16*)d_ws;

    if (ws_size >= WS_NEED) {
        hipLaunchKernelGGL(xfrag_prep, dim3(NBLK * 8), dim3(256), 0, stream, X, xw);
        hipLaunchKernelGGL(lstm_mfma4<1>, dim3(NBLK), dim3(512), 0, stream,
                           X, xw, W1ih, W1hh, b1i, b1h, W2ih, W2hh, b2i, b2h,
                           fc1w, fc1b, fc2w, fc2b, (float*)d_out);
    } else {
        hipLaunchKernelGGL(lstm_mfma4<0>, dim3(NBLK), dim3(512), 0, stream,
                           X, xw, W1ih, W1hh, b1i, b1h, W2ih, W2hh, b2i, b2h,
                           fc1w, fc1b, fc2w, fc2b, (float*)d_out);
    }
}